// Round 2
// baseline (74.923 us; speedup 1.0000x reference)
//
#include <hip/hip_runtime.h>
#include <math.h>

// DiffEMA: out[t] = sum_{k=0}^{K-1} alpha*(1-alpha)^k * x[t-k], x[<0]=x[0]
// Computed exactly as out[t] = y[t] - c^K * y[t-K], c = 1-alpha,
// y = infinite IIR: y[t] = c*y[t-1] + alpha*x[t].
// Each block handles NB outputs; scans EXT extra positions before its chunk
// with zero init (error <= c^(EXT-K)*max|y| ~ 8e-9, negligible).

#define K_TAPS 700
#define NB     4096            // outputs per block
#define EXT    2560            // warm-up + K region staged before block start
#define TOTAL  (NB + EXT)      // 6656 staged samples
#define BLOCK  256
#define LSEG   (TOTAL / BLOCK) // 26 samples per thread segment

__global__ __launch_bounds__(BLOCK)
void diffema_kernel(const float* __restrict__ x,
                    const float* __restrict__ w_alpha,
                    float* __restrict__ out,
                    int T) {
    __shared__ float xs[TOTAL];
    __shared__ float ys[TOTAL];
    __shared__ float wP[BLOCK / 64];
    __shared__ float wV[BLOCK / 64];

    const int tid = threadIdx.x;
    const int bid = blockIdx.x;
    const int t0  = bid * NB;          // first output index of this block
    const int base = t0 - EXT;         // first staged sample (may be < 0)

    // alpha from logit parameter (device scalar; accurate exp/pow, once/thread)
    const float w     = w_alpha[0];
    const float alpha = 1.0f / (1.0f + expf(-w));
    const float c     = 1.0f - alpha;
    const float cK    = powf(c, (float)K_TAPS);
    const float cL    = powf(c, (float)LSEG);

    // ---- stage x into LDS (clamp negative indices to 0: left-pad with x[0])
    for (int j = tid; j < TOTAL; j += BLOCK) {
        int p = base + j;
        if (p < 0) p = 0;
        xs[j] = x[p];
    }
    __syncthreads();

    // ---- per-thread local scan with zero init: segment value V, decay P=c^LSEG
    const int s0 = tid * LSEG;
    float v = 0.0f;
#pragma unroll
    for (int j = 0; j < LSEG; ++j) {
        v = c * v + alpha * xs[s0 + j];
    }

    // ---- wave-level inclusive scan of (P,V) under composition
    //      (prev then mine): V <- P_mine*V_prev + V_mine ; P <- P_mine*P_prev
    float P = cL, V = v;
    const int lane = tid & 63;
#pragma unroll
    for (int d = 1; d < 64; d <<= 1) {
        float Pp = __shfl_up(P, d);
        float Vp = __shfl_up(V, d);
        if (lane >= d) {
            V = P * Vp + V;   // uses pre-update P (mine)
            P = P * Pp;
        }
    }

    // ---- cross-wave: wave aggregates -> LDS, compose serially (<=3 iters)
    const int wave = tid >> 6;
    if (lane == 63) { wP[wave] = P; wV[wave] = V; }
    __syncthreads();

    float prefV = 0.0f;                 // scan value at end of previous waves
    for (int k = 0; k < wave; ++k) {
        prefV = wP[k] * prefV + wV[k];
    }

    // exclusive within wave: state at end of lane-1's segment
    float Pex = __shfl_up(P, 1);
    float Vex = __shfl_up(V, 1);
    if (lane == 0) { Pex = 1.0f; Vex = 0.0f; }
    float s = Pex * prefV + Vex;        // true init state for my segment

    // ---- re-scan with true init, write y to LDS
#pragma unroll
    for (int j = 0; j < LSEG; ++j) {
        s = c * s + alpha * xs[s0 + j];
        ys[s0 + j] = s;
    }
    __syncthreads();

    // ---- combine: out[t] = y[t] - c^K * y[t-K], coalesced
#pragma unroll 4
    for (int j = tid; j < NB; j += BLOCK) {
        int q = EXT + j;
        out[t0 + j] = ys[q] - cK * ys[q - K_TAPS];
    }
}

extern "C" void kernel_launch(void* const* d_in, const int* in_sizes, int n_in,
                              void* d_out, int out_size, void* d_ws, size_t ws_size,
                              hipStream_t stream) {
    const float* x       = (const float*)d_in[0];
    const float* w_alpha = (const float*)d_in[1];
    float*       out     = (float*)d_out;
    const int T = in_sizes[0];

    const int nblocks = (T + NB - 1) / NB;   // 1024 for T=4194304
    diffema_kernel<<<nblocks, BLOCK, 0, stream>>>(x, w_alpha, out, T);
}